// Round 16
// baseline (673.980 us; speedup 1.0000x reference)
//
#include <hip/hip_runtime.h>

// LSTM B=512,T=512,D=128,H=64,O=1. Gate order i,f,g,o.
// K1: pre = x@Wih0^T + bih0+bhh0 — fp16 MFMA (R15: ~70us, near 64us HBM floor).
// K2 (R16 redesign): gate-colocated quads + single barrier.
//   R15 counters: k_fused 571us = 89% of total, DS-issue-bound (14 LDS inst/thr/step,
//   2 barriers, serialized updater phase with scattered zl b32 reads).
//   New: quad owns the 4 GATE-rows of one unit -> after select-free xor1/xor2
//   merge (R13-proven), 2 DPP movs gather all 4 gates into one lane -> cell
//   update inline, zl GONE. L1 quads own Wih1 AND Whh1 rows of their unit
//   (two 4-slot groups, same rofs pattern each, summed) -> z1 in-quad.
//   Layer skew => all reads parity p, writes p^1 => ONE barrier/step.
//   512 thr/block (waves 0-3: layer0, 4-7: layer1), 256 blocks, C=2 batches.
// ws: 512*512*256*4 = 256 MiB fp32 pre (written by K1, read-only in K2).

#define TSTEPS 512

typedef _Float16 h2v __attribute__((ext_vector_type(2)));
typedef _Float16 half8 __attribute__((ext_vector_type(8)));
typedef __attribute__((ext_vector_type(4))) float facc;
union HU { unsigned u; h2v h; };

__device__ __forceinline__ float sigf(float x){ return 1.0f/(1.0f+__expf(-x)); }
__device__ __forceinline__ float tanh_fast(float x){
  float ax=fabsf(x); float e=__expf(-2.0f*ax); float r=(1.0f-e)/(1.0f+e); return copysignf(r,x);
}
__device__ __forceinline__ unsigned packh(float a, float b){
  unsigned short la = __builtin_bit_cast(unsigned short, (_Float16)a);
  unsigned short lb = __builtin_bit_cast(unsigned short, (_Float16)b);
  return (unsigned)la | ((unsigned)lb << 16);
}
__device__ __forceinline__ float dot2f(unsigned wu, unsigned hu, float acc){
#if __has_builtin(__builtin_amdgcn_fdot2)
  HU w; w.u = wu; HU x; x.u = hu;
  return __builtin_amdgcn_fdot2(w.h, x.h, acc, false);
#else
  HU w; w.u = wu; HU x; x.u = hu;
  acc = fmaf((float)w.h[0], (float)x.h[0], acc);
  acc = fmaf((float)w.h[1], (float)x.h[1], acc);
  return acc;
#endif
}
// CTRL: 0xB1 = quad_perm [1,0,3,2] (xor1), 0x4E = [2,3,0,1] (xor2)
template<int CTRL>
__device__ __forceinline__ float add_dpp(float a, float b){
  return a + __int_as_float(__builtin_amdgcn_update_dpp(
      0, __float_as_int(b), CTRL, 0xF, 0xF, true));
}
template<int CTRL>
__device__ __forceinline__ float mov_dpp(float b){
  return __int_as_float(__builtin_amdgcn_update_dpp(
      0, __float_as_int(b), CTRL, 0xF, 0xF, true));
}
// 16-k fp16 dot: w(2 uint4) . h(2 uint4)
__device__ __forceinline__ float dot16(uint4 w0, uint4 w1, uint4 h0, uint4 h1){
  float a = 0.0f;
  a = dot2f(w0.x, h0.x, a); a = dot2f(w0.y, h0.y, a);
  a = dot2f(w0.z, h0.z, a); a = dot2f(w0.w, h0.w, a);
  a = dot2f(w1.x, h1.x, a); a = dot2f(w1.y, h1.y, a);
  a = dot2f(w1.z, h1.z, a); a = dot2f(w1.w, h1.w, a);
  return a;
}

// ---------------- K1: input projection GEMM (fp16 MFMA) ----------------
__global__ __launch_bounds__(256) void k_inproj(
    const float* __restrict__ x, const float* __restrict__ W,
    const float* __restrict__ bih, const float* __restrict__ bhh,
    float* __restrict__ pre)
{
    __shared__ __align__(16) _Float16 Ah[64][136];
    __shared__ __align__(16) _Float16 Bh[256][136];
    const int tid = threadIdx.x;
    const long row0 = (long)blockIdx.x * 64;

    {
        const int r = tid >> 2, c0 = (tid & 3) * 32;
        const float4* src = (const float4*)(x + (row0 + r) * 128 + c0);
#pragma unroll
        for (int i = 0; i < 4; ++i) {
            float4 v0 = src[2 * i], v1 = src[2 * i + 1];
            half8 hv = { (_Float16)v0.x, (_Float16)v0.y, (_Float16)v0.z, (_Float16)v0.w,
                         (_Float16)v1.x, (_Float16)v1.y, (_Float16)v1.z, (_Float16)v1.w };
            *(half8*)&Ah[r][c0 + 8 * i] = hv;
        }
    }
    {
        const float4* src = (const float4*)(W + tid * 128);
#pragma unroll
        for (int i = 0; i < 16; ++i) {
            float4 v0 = src[2 * i], v1 = src[2 * i + 1];
            half8 hv = { (_Float16)v0.x, (_Float16)v0.y, (_Float16)v0.z, (_Float16)v0.w,
                         (_Float16)v1.x, (_Float16)v1.y, (_Float16)v1.z, (_Float16)v1.w };
            *(half8*)&Bh[tid][8 * i] = hv;
        }
    }
    __syncthreads();

    const int w  = tid >> 6;
    const int l  = tid & 63;
    const int lm = l & 15;
    const int lk = l >> 4;
    const int n0 = w * 64;

    facc acc[4][4];
#pragma unroll
    for (int mi = 0; mi < 4; ++mi)
#pragma unroll
        for (int ni = 0; ni < 4; ++ni) acc[mi][ni] = (facc){0.f, 0.f, 0.f, 0.f};

#pragma unroll
    for (int ks = 0; ks < 4; ++ks) {
        const int kk = ks * 32 + lk * 8;
        half8 Af[4], Bf[4];
#pragma unroll
        for (int mi = 0; mi < 4; ++mi) Af[mi] = *(const half8*)&Ah[mi * 16 + lm][kk];
#pragma unroll
        for (int ni = 0; ni < 4; ++ni) Bf[ni] = *(const half8*)&Bh[n0 + ni * 16 + lm][kk];
#pragma unroll
        for (int mi = 0; mi < 4; ++mi)
#pragma unroll
            for (int ni = 0; ni < 4; ++ni)
                acc[mi][ni] = __builtin_amdgcn_mfma_f32_16x16x32_f16(
                    Af[mi], Bf[ni], acc[mi][ni], 0, 0, 0);
    }

    float bs[4];
#pragma unroll
    for (int ni = 0; ni < 4; ++ni) {
        const int n = n0 + ni * 16 + lm;
        bs[ni] = bih[n] + bhh[n];
    }
#pragma unroll
    for (int mi = 0; mi < 4; ++mi) {
#pragma unroll
        for (int ni = 0; ni < 4; ++ni) {
            const int n = n0 + ni * 16 + lm;
#pragma unroll
            for (int r = 0; r < 4; ++r) {
                const long row = row0 + mi * 16 + lk * 4 + r;
                pre[row * 256 + n] = acc[mi][ni][r] + bs[ni];
            }
        }
    }
}

// ---------------- K2: fused 2-layer recurrence + head ----------------
// 256 blocks x 512 thr. Waves 0-3: layer-0 quads (unit u = (tid&255)>>2);
// waves 4-7: layer-1 quads. Lane ll=tid&3 owns k-slice [16ll,16ll+16).
__global__ __attribute__((amdgpu_flat_work_group_size(512, 512)))
void k_fused(
    const float* __restrict__ Whh0, const float* __restrict__ Wih1,
    const float* __restrict__ Whh1,
    const float* __restrict__ bih1, const float* __restrict__ bhh1,
    const float* __restrict__ Wfc,  const float* __restrict__ bfc,
    const float* __restrict__ pre,  float* __restrict__ out)
{
    const int tid  = threadIdx.x;
    const bool isL1 = tid >= 256;
    const int t2  = tid & 255;
    const int u   = t2 >> 2;          // hidden unit 0..63
    const int ll  = t2 & 3;           // lane-in-quad
    const int cA  = (ll >> 1) & 1;    // surviving batch slot
    const int cB  = cA ^ 1;
    const long bb = (long)blockIdx.x * 2;

    __shared__ __align__(16) uint4 wl0[8][256];    // 32KB Whh0 streams
    __shared__ __align__(16) uint4 wl1[16][256];   // 64KB Wih1+Whh1 streams
    __shared__ unsigned hp[2][2][2][32];           // 1KB [par][batch][layer] 64 fp16
    __shared__ float hfin[2][64];

    // slot s holds gate rofs[s]; pairing makes xor1/xor2 merges select-free (R13)
    const int rofs[4] = { (ll & 1), 2 + (ll & 1), 1 - (ll & 1), 3 - (ll & 1) };

    // ---- one-time weight packing into per-thread fp16 streams ----
    if (!isL1) {
#pragma unroll
        for (int s = 0; s < 4; ++s) {
            const int row = rofs[s] * 64 + u;
            const float4* src = (const float4*)(Whh0 + row * 64 + 16 * ll);
            float4 f0 = src[0], f1 = src[1], f2 = src[2], f3 = src[3];
            uint4 u0 = { packh(f0.x,f0.y), packh(f0.z,f0.w), packh(f1.x,f1.y), packh(f1.z,f1.w) };
            uint4 u1 = { packh(f2.x,f2.y), packh(f2.z,f2.w), packh(f3.x,f3.y), packh(f3.z,f3.w) };
            wl0[2 * s + 0][t2] = u0;
            wl0[2 * s + 1][t2] = u1;
        }
    } else {
#pragma unroll
        for (int s = 0; s < 4; ++s) {
            const int row = rofs[s] * 64 + u;
            const float4* sa = (const float4*)(Wih1 + row * 64 + 16 * ll);
            float4 f0 = sa[0], f1 = sa[1], f2 = sa[2], f3 = sa[3];
            uint4 a0 = { packh(f0.x,f0.y), packh(f0.z,f0.w), packh(f1.x,f1.y), packh(f1.z,f1.w) };
            uint4 a1 = { packh(f2.x,f2.y), packh(f2.z,f2.w), packh(f3.x,f3.y), packh(f3.z,f3.w) };
            wl1[2 * s + 0][t2] = a0;
            wl1[2 * s + 1][t2] = a1;
            const float4* sb = (const float4*)(Whh1 + row * 64 + 16 * ll);
            float4 g0 = sb[0], g1 = sb[1], g2 = sb[2], g3 = sb[3];
            uint4 b0 = { packh(g0.x,g0.y), packh(g0.z,g0.w), packh(g1.x,g1.y), packh(g1.z,g1.w) };
            uint4 b1 = { packh(g2.x,g2.y), packh(g2.z,g2.w), packh(g3.x,g3.y), packh(g3.z,g3.w) };
            wl1[8 + 2 * s + 0][t2] = b0;
            wl1[8 + 2 * s + 1][t2] = b1;
        }
    }
    if (tid < 256) ((unsigned*)hp)[tid] = 0;   // h_{-1}=h_{-2}=0 both parities

    // cell-lane constants
    float bias1v[4] = {0, 0, 0, 0};
    float pc[4] = {0, 0, 0, 0};
    const float* pb = pre + (bb + cA) * (long)(TSTEPS * 256);
    if (!isL1 && !(ll & 1)) {
#pragma unroll
        for (int g = 0; g < 4; ++g) pc[g] = pb[g * 64 + u];   // t=0
    }
    if (isL1 && !(ll & 1)) {
#pragma unroll
        for (int g = 0; g < 4; ++g) bias1v[g] = bih1[g * 64 + u] + bhh1[g * 64 + u];
    }

    float cst = 0.0f, h1keep = 0.0f;
    int p = 0;
    __syncthreads();

#pragma unroll 1
    for (int n = 0; n <= TSTEPS; ++n) {
        if (!isL1) {
            // ---- layer 0: z0 = pre(t=n) + Whh0 . h0(n-1) ----
            float pn[4] = {0, 0, 0, 0};
            if (!(ll & 1)) {
                const int tn = (n + 1 < TSTEPS) ? n + 1 : 0;
#pragma unroll
                for (int g = 0; g < 4; ++g) pn[g] = pb[tn * 256 + g * 64 + u];
            }
            uint4 hA0 = *(const uint4*)&hp[p][cA][0][ll * 8];
            uint4 hA1 = *(const uint4*)&hp[p][cA][0][ll * 8 + 4];
            uint4 hB0 = *(const uint4*)&hp[p][cB][0][ll * 8];
            uint4 hB1 = *(const uint4*)&hp[p][cB][0][ll * 8 + 4];

            float pA[4], pB[4];
#pragma unroll
            for (int s = 0; s < 4; ++s) {
                uint4 w0 = wl0[2 * s + 0][t2];
                uint4 w1 = wl0[2 * s + 1][t2];
                pA[s] = dot16(w0, w1, hA0, hA1);
                pB[s] = dot16(w0, w1, hB0, hB1);
            }
            float q0A = add_dpp<0xB1>(pA[0], pA[2]);
            float q1A = add_dpp<0xB1>(pA[1], pA[3]);
            float q0B = add_dpp<0xB1>(pB[0], pB[2]);
            float q1B = add_dpp<0xB1>(pB[1], pB[3]);
            float r0 = add_dpp<0x4E>(q0A, q0B);   // gate (ll&1),   batch cA
            float r1 = add_dpp<0x4E>(q1A, q1B);   // gate (ll&1)+2, batch cA
            float o0 = mov_dpp<0xB1>(r0);         // gate (ll&1)^1
            float o1 = mov_dpp<0xB1>(r1);         // gate ((ll&1)^1)+2

            if (!(ll & 1) && n < TSTEPS) {
                // lane ll in {0,2}: gates i=r0, f=o0, g=r1, o=o1 of (u, batch cA)
                float i_ = sigf(pc[0] + r0);
                float f_ = sigf(pc[1] + o0);
                float g_ = tanh_fast(pc[2] + r1);
                float o_ = sigf(pc[3] + o1);
                cst = fmaf(f_, cst, i_ * g_);
                float h = o_ * tanh_fast(cst);
                ((unsigned short*)&hp[p ^ 1][cA][0][0])[u] =
                    __builtin_bit_cast(unsigned short, (_Float16)h);
                pc[0] = pn[0]; pc[1] = pn[1]; pc[2] = pn[2]; pc[3] = pn[3];
            }
        } else {
            // ---- layer 1 (t=n-1): z1 = b1 + Wih1 . h0(n-1) + Whh1 . h1(n-2) ----
            uint4 xA0 = *(const uint4*)&hp[p][cA][0][ll * 8];
            uint4 xA1 = *(const uint4*)&hp[p][cA][0][ll * 8 + 4];
            uint4 xB0 = *(const uint4*)&hp[p][cB][0][ll * 8];
            uint4 xB1 = *(const uint4*)&hp[p][cB][0][ll * 8 + 4];
            uint4 yA0 = *(const uint4*)&hp[p][cA][1][ll * 8];
            uint4 yA1 = *(const uint4*)&hp[p][cA][1][ll * 8 + 4];
            uint4 yB0 = *(const uint4*)&hp[p][cB][1][ll * 8];
            uint4 yB1 = *(const uint4*)&hp[p][cB][1][ll * 8 + 4];

            float aA[4], aB[4], bA[4], bB[4];
#pragma unroll
            for (int s = 0; s < 4; ++s) {
                uint4 w0 = wl1[2 * s + 0][t2];
                uint4 w1 = wl1[2 * s + 1][t2];
                aA[s] = dot16(w0, w1, xA0, xA1);
                aB[s] = dot16(w0, w1, xB0, xB1);
                uint4 v0 = wl1[8 + 2 * s + 0][t2];
                uint4 v1 = wl1[8 + 2 * s + 1][t2];
                bA[s] = dot16(v0, v1, yA0, yA1);
                bB[s] = dot16(v0, v1, yB0, yB1);
            }
            float qa0A = add_dpp<0xB1>(aA[0], aA[2]);
            float qa1A = add_dpp<0xB1>(aA[1], aA[3]);
            float qa0B = add_dpp<0xB1>(aB[0], aB[2]);
            float qa1B = add_dpp<0xB1>(aB[1], aB[3]);
            float ra0 = add_dpp<0x4E>(qa0A, qa0B);
            float ra1 = add_dpp<0x4E>(qa1A, qa1B);
            float qb0A = add_dpp<0xB1>(bA[0], bA[2]);
            float qb1A = add_dpp<0xB1>(bA[1], bA[3]);
            float qb0B = add_dpp<0xB1>(bB[0], bB[2]);
            float qb1B = add_dpp<0xB1>(bB[1], bB[3]);
            float rb0 = add_dpp<0x4E>(qb0A, qb0B);
            float rb1 = add_dpp<0x4E>(qb1A, qb1B);
            float r0 = ra0 + rb0;                 // gate (ll&1),   batch cA
            float r1 = ra1 + rb1;                 // gate (ll&1)+2, batch cA
            float o0 = mov_dpp<0xB1>(r0);
            float o1 = mov_dpp<0xB1>(r1);

            if (!(ll & 1) && n >= 1) {
                float i_ = sigf(bias1v[0] + r0);
                float f_ = sigf(bias1v[1] + o0);
                float g_ = tanh_fast(bias1v[2] + r1);
                float o_ = sigf(bias1v[3] + o1);
                cst = fmaf(f_, cst, i_ * g_);
                float h = o_ * tanh_fast(cst);
                h1keep = h;
                ((unsigned short*)&hp[p ^ 1][cA][1][0])[u] =
                    __builtin_bit_cast(unsigned short, (_Float16)h);
            }
        }
        __syncthreads();
        p ^= 1;
    }

    // ---- head: out[bb+c] = h1(T-1) . Wfc + bfc ----
    if (isL1 && !(ll & 1)) hfin[cA][u] = h1keep;
    __syncthreads();
    if (tid < 128) {
        const int c = tid >> 6, j = tid & 63;
        float v = hfin[c][j] * Wfc[j];
#pragma unroll
        for (int off = 32; off > 0; off >>= 1) v += __shfl_down(v, off);
        if ((tid & 63) == 0) out[bb + c] = v + bfc[0];
    }
}

extern "C" void kernel_launch(void* const* d_in, const int* in_sizes, int n_in,
                              void* d_out, int out_size, void* d_ws, size_t ws_size,
                              hipStream_t stream)
{
    const float* x    = (const float*)d_in[0];
    const float* Wih0 = (const float*)d_in[1];
    const float* Whh0 = (const float*)d_in[2];
    const float* bih0 = (const float*)d_in[3];
    const float* bhh0 = (const float*)d_in[4];
    const float* Wih1 = (const float*)d_in[5];
    const float* Whh1 = (const float*)d_in[6];
    const float* bih1 = (const float*)d_in[7];
    const float* bhh1 = (const float*)d_in[8];
    const float* Wfc  = (const float*)d_in[9];
    const float* bfc  = (const float*)d_in[10];
    float* out = (float*)d_out;
    float* pre = (float*)d_ws;  // [B][T][256] fp32 = 256 MiB

    k_inproj<<<4096, 256, 0, stream>>>(x, Wih0, bih0, bhh0, pre);
    k_fused<<<256, 512, 0, stream>>>(Whh0, Wih1, Whh1, bih1, bhh1, Wfc, bfc, pre, out);
}